// Round 2
// baseline (31542.676 us; speedup 1.0000x reference)
//
#include <hip/hip_runtime.h>
#include <hip/hip_bf16.h>
#include <hip/hip_cooperative_groups.h>

namespace cg = cooperative_groups;

typedef __bf16 bf16_t;
typedef bf16_t bf16x8 __attribute__((ext_vector_type(8)));
typedef float f32x4 __attribute__((ext_vector_type(4)));

#define T_SEQ 512
#define NB 128
#define HID 1024
#define FIN 64
#define LD0 1088                 // 64 + 1024
#define LD1 2048                 // 1024 + 1024
#define HB (NB * HID)            // h/c state elements per layer
#define LDS_STRIDE0 1096         // 1088 + 8 pad (2-way bank conflict only)
#define LDS_STRIDE1 2056         // 2048 + 8 pad
#define LDS_BYTES (64 * LDS_STRIDE0 * 2)  // 140288 B (max of both layers)

__device__ __forceinline__ float sigm_f(float x) { return 1.0f / (1.0f + __expf(-x)); }
__device__ __forceinline__ float tanh_f(float x) { return 2.0f * sigm_f(2.0f * x) - 1.0f; }

// One-shot prep: bf16 weight repack [W_ih | W_hh], bf16 x and Wfc, combined
// biases, zeroed states. Runs every call (ws is re-poisoned by the harness).
__global__ __launch_bounds__(256) void prep_kernel(
    const float* __restrict__ x,
    const float* __restrict__ Wih0, const float* __restrict__ Whh0,
    const float* __restrict__ bih0, const float* __restrict__ bhh0,
    const float* __restrict__ Wih1, const float* __restrict__ Whh1,
    const float* __restrict__ bih1, const float* __restrict__ bhh1,
    const float* __restrict__ Wfc,
    bf16_t* __restrict__ Wcat0, bf16_t* __restrict__ Wcat1,
    bf16_t* __restrict__ xbf, bf16_t* __restrict__ Wfcb,
    float* __restrict__ bias0, float* __restrict__ bias1,
    bf16_t* __restrict__ h0s, bf16_t* __restrict__ h1s,
    float* __restrict__ c0, float* __restrict__ c1)
{
    const unsigned stride = gridDim.x * blockDim.x;
    const unsigned i0 = blockIdx.x * blockDim.x + threadIdx.x;

    for (unsigned i = i0; i < 4096u * LD1; i += stride) {
        unsigned m = i >> 11, kk = i & 2047u;
        float v = (kk < HID) ? Wih1[m * HID + kk] : Whh1[m * HID + (kk - HID)];
        Wcat1[i] = (bf16_t)v;
    }
    for (unsigned i = i0; i < 4096u * LD0; i += stride) {
        unsigned m = i / LD0, kk = i - m * LD0;
        float v = (kk < FIN) ? Wih0[m * FIN + kk] : Whh0[m * HID + (kk - FIN)];
        Wcat0[i] = (bf16_t)v;
    }
    for (unsigned i = i0; i < (unsigned)(NB * T_SEQ * FIN); i += stride)
        xbf[i] = (bf16_t)x[i];
    for (unsigned i = i0; i < 64u * HID; i += stride)
        Wfcb[i] = (bf16_t)Wfc[i];
    for (unsigned i = i0; i < 2u * HB; i += stride) {
        h0s[i] = (bf16_t)0.0f; h1s[i] = (bf16_t)0.0f;
    }
    for (unsigned i = i0; i < (unsigned)HB; i += stride) { c0[i] = 0.0f; c1[i] = 0.0f; }
    for (unsigned i = i0; i < 4096u; i += stride) {
        bias0[i] = bih0[i] + bhh0[i];
        bias1[i] = bih1[i] + bhh1[i];
    }
}

// Persistent cooperative kernel. 256 blocks x 512 threads, 1 block/CU.
// Blocks 0..127: layer0 (64 gate-rows = 16 hidden x 4 gates, 64-batch tile).
// Blocks 128..255: layer1 (32 gate-rows = 8 hidden x 4 gates, full 128 batch).
// Weights LDS-resident (rows ordered u*4+gate so the cell update is lane-local).
// Pipeline: interval k runs L0@t=k and L1@t=k-1; one grid.sync per interval.
__global__ __launch_bounds__(512, 2) void lstm_persist(
    const bf16_t* __restrict__ Wcat0, const bf16_t* __restrict__ Wcat1,
    const float* __restrict__ bias0, const float* __restrict__ bias1,
    const bf16_t* __restrict__ xbf,
    bf16_t* __restrict__ h0s,   // [2][NB][HID] layer0 h ping-pong
    bf16_t* __restrict__ h1x,   // [2][NB][HID] layer0 output -> layer1 input
    bf16_t* __restrict__ h1s,   // [2][NB][HID] layer1 h ping-pong
    float* __restrict__ c0, float* __restrict__ c1,  // [HID][NB] fp32
    bf16_t* __restrict__ h2buf) // [NB][T][HID] layer1 h history for FC
{
    extern __shared__ bf16_t Wl[];
    cg::grid_group grid = cg::this_grid();

    const int b = blockIdx.x;
    const int tid = threadIdx.x;
    const int layer = b >> 7;

    // ---- one-time weight gather into LDS ----
    if (layer == 0) {
        const int g0 = b >> 1;
        for (int c = tid; c < 64 * (LD0 / 8); c += 512) {
            int r = c / (LD0 / 8), off = (c % (LD0 / 8)) * 8;
            int u = r >> 2, gate = r & 3;
            int grow = gate * HID + g0 * 16 + u;
            *(bf16x8*)(Wl + r * LDS_STRIDE0 + off) =
                *(const bf16x8*)(Wcat0 + (size_t)grow * LD0 + off);
        }
    } else {
        const int g1 = b & 127;
        for (int c = tid; c < 32 * (LD1 / 8); c += 512) {
            int r = c >> 8, off = (c & 255) * 8;
            int u = r >> 2, gate = r & 3;
            int grow = gate * HID + g1 * 8 + u;
            *(bf16x8*)(Wl + r * LDS_STRIDE1 + off) =
                *(const bf16x8*)(Wcat1 + (size_t)grow * LD1 + off);
        }
    }
    __syncthreads();

    const int wv = tid >> 6;
    const int lane = tid & 63;
    const int q = lane >> 4;
    const int l = lane & 15;

    for (int k = 0; k <= T_SEQ; ++k) {
        if (layer == 0) {
            const int t = k;
            if (t < T_SEQ) {
                const int g0 = b >> 1, bt = b & 1;
                const int mt = wv >> 1, nt = wv & 1;  // 4 M-tiles x 2 N-tiles
                const int n0 = bt * 64 + nt * 32;
                const int nA = n0 + l, nB = n0 + 16 + l;
                const bf16_t* ar = Wl + (mt * 16 + l) * LDS_STRIDE0 + q * 8;
                const bf16_t* h0r = h0s + (size_t)(t & 1) * HB;
                f32x4 a0 = {0.f, 0.f, 0.f, 0.f}, a1 = {0.f, 0.f, 0.f, 0.f};

                const bf16_t* xA = xbf + ((size_t)nA * T_SEQ + t) * FIN + q * 8;
                const bf16_t* xB = xbf + ((size_t)nB * T_SEQ + t) * FIN + q * 8;
#pragma unroll
                for (int p = 0; p < 2; ++p) {
                    bf16x8 av = *(const bf16x8*)(ar + p * 32);
                    a0 = __builtin_amdgcn_mfma_f32_16x16x32_bf16(av, *(const bf16x8*)(xA + p * 32), a0, 0, 0, 0);
                    a1 = __builtin_amdgcn_mfma_f32_16x16x32_bf16(av, *(const bf16x8*)(xB + p * 32), a1, 0, 0, 0);
                }
                const bf16_t* hA = h0r + (size_t)nA * HID + q * 8;
                const bf16_t* hB = h0r + (size_t)nB * HID + q * 8;
#pragma unroll 4
                for (int p = 0; p < 32; ++p) {
                    bf16x8 av = *(const bf16x8*)(ar + FIN + p * 32);
                    a0 = __builtin_amdgcn_mfma_f32_16x16x32_bf16(av, *(const bf16x8*)(hA + p * 32), a0, 0, 0, 0);
                    a1 = __builtin_amdgcn_mfma_f32_16x16x32_bf16(av, *(const bf16x8*)(hB + p * 32), a1, 0, 0, 0);
                }
                // lane-local cell update: lane holds gates i,f,g,o in acc[0..3]
                const int u = mt * 4 + q, j = g0 * 16 + u;
                const float bi = bias0[j], bff = bias0[HID + j],
                            bg = bias0[2 * HID + j], bo = bias0[3 * HID + j];
                bf16_t* h0w  = h0s + (size_t)((t + 1) & 1) * HB;
                bf16_t* h1xw = h1x + (size_t)(t & 1) * HB;
#pragma unroll
                for (int s = 0; s < 2; ++s) {
                    f32x4 ac = s ? a1 : a0;
                    const int n = n0 + s * 16 + l;
                    float iv = sigm_f(ac[0] + bi);
                    float fv = sigm_f(ac[1] + bff);
                    float gv = tanh_f(ac[2] + bg);
                    float ov = sigm_f(ac[3] + bo);
                    size_t ci = (size_t)j * NB + n;
                    float cn = fv * c0[ci] + iv * gv;
                    c0[ci] = cn;
                    bf16_t hv = (bf16_t)(ov * tanh_f(cn));
                    h0w[(size_t)n * HID + j] = hv;
                    h1xw[(size_t)n * HID + j] = hv;
                }
            }
        } else {
            const int t = k - 1;
            if (t >= 0) {
                const int g1 = b & 127;
                const int mt = wv >> 2, nt = wv & 3;  // 2 M-tiles x 4 N-tiles
                const int n0 = nt * 32;
                const int nA = n0 + l, nB = n0 + 16 + l;
                const bf16_t* ar = Wl + (mt * 16 + l) * LDS_STRIDE1 + q * 8;
                const bf16_t* xr = h1x + (size_t)(t & 1) * HB;
                const bf16_t* hr = h1s + (size_t)(t & 1) * HB;
                f32x4 a0 = {0.f, 0.f, 0.f, 0.f}, a1 = {0.f, 0.f, 0.f, 0.f};

                const bf16_t* xA = xr + (size_t)nA * HID + q * 8;
                const bf16_t* xB = xr + (size_t)nB * HID + q * 8;
#pragma unroll 4
                for (int p = 0; p < 32; ++p) {
                    bf16x8 av = *(const bf16x8*)(ar + p * 32);
                    a0 = __builtin_amdgcn_mfma_f32_16x16x32_bf16(av, *(const bf16x8*)(xA + p * 32), a0, 0, 0, 0);
                    a1 = __builtin_amdgcn_mfma_f32_16x16x32_bf16(av, *(const bf16x8*)(xB + p * 32), a1, 0, 0, 0);
                }
                const bf16_t* hA = hr + (size_t)nA * HID + q * 8;
                const bf16_t* hB = hr + (size_t)nB * HID + q * 8;
#pragma unroll 4
                for (int p = 0; p < 32; ++p) {
                    bf16x8 av = *(const bf16x8*)(ar + HID + p * 32);
                    a0 = __builtin_amdgcn_mfma_f32_16x16x32_bf16(av, *(const bf16x8*)(hA + p * 32), a0, 0, 0, 0);
                    a1 = __builtin_amdgcn_mfma_f32_16x16x32_bf16(av, *(const bf16x8*)(hB + p * 32), a1, 0, 0, 0);
                }
                const int u = mt * 4 + q, j = g1 * 8 + u;
                const float bi = bias1[j], bff = bias1[HID + j],
                            bg = bias1[2 * HID + j], bo = bias1[3 * HID + j];
                bf16_t* h1w = h1s + (size_t)((t + 1) & 1) * HB;
#pragma unroll
                for (int s = 0; s < 2; ++s) {
                    f32x4 ac = s ? a1 : a0;
                    const int n = n0 + s * 16 + l;
                    float iv = sigm_f(ac[0] + bi);
                    float fv = sigm_f(ac[1] + bff);
                    float gv = tanh_f(ac[2] + bg);
                    float ov = sigm_f(ac[3] + bo);
                    size_t ci = (size_t)j * NB + n;
                    float cn = fv * c1[ci] + iv * gv;
                    c1[ci] = cn;
                    bf16_t hv = (bf16_t)(ov * tanh_f(cn));
                    h1w[(size_t)n * HID + j] = hv;
                    h2buf[((size_t)n * T_SEQ + t) * HID + j] = hv;
                }
            }
        }
        grid.sync();
    }
}

// Final FC: out[m][o] = h2[m][:] @ Wfc[o][:] + bfc[o], m = b*T + t (65536 rows).
__global__ __launch_bounds__(256) void fc_kernel(
    const bf16_t* __restrict__ h2buf, const bf16_t* __restrict__ Wfcb,
    const float* __restrict__ bfc, float* __restrict__ out)
{
    const int tid = threadIdx.x, wv = tid >> 6, lane = tid & 63;
    const int q = lane >> 4, l = lane & 15;
    const int m0 = blockIdx.x * 64 + wv * 16;
    const bf16_t* arow = h2buf + (size_t)(m0 + l) * HID + q * 8;
    const bf16_t* brow = Wfcb + (size_t)l * HID + q * 8;
    f32x4 acc[4] = {{0.f,0.f,0.f,0.f},{0.f,0.f,0.f,0.f},{0.f,0.f,0.f,0.f},{0.f,0.f,0.f,0.f}};
#pragma unroll 4
    for (int p = 0; p < 32; ++p) {
        bf16x8 av = *(const bf16x8*)(arow + p * 32);
#pragma unroll
        for (int ntile = 0; ntile < 4; ++ntile) {
            bf16x8 bv = *(const bf16x8*)(brow + (size_t)ntile * 16 * HID + p * 32);
            acc[ntile] = __builtin_amdgcn_mfma_f32_16x16x32_bf16(av, bv, acc[ntile], 0, 0, 0);
        }
    }
#pragma unroll
    for (int ntile = 0; ntile < 4; ++ntile) {
        float bv = bfc[ntile * 16 + l];
#pragma unroll
        for (int r = 0; r < 4; ++r)
            out[(size_t)(m0 + q * 4 + r) * 64 + ntile * 16 + l] = acc[ntile][r] + bv;
    }
}

extern "C" void kernel_launch(void* const* d_in, const int* in_sizes, int n_in,
                              void* d_out, int out_size, void* d_ws, size_t ws_size,
                              hipStream_t stream)
{
    const float* x    = (const float*)d_in[0];
    const float* Wih0 = (const float*)d_in[1];
    const float* Whh0 = (const float*)d_in[2];
    const float* bih0 = (const float*)d_in[3];
    const float* bhh0 = (const float*)d_in[4];
    const float* Wih1 = (const float*)d_in[5];
    const float* Whh1 = (const float*)d_in[6];
    const float* bih1 = (const float*)d_in[7];
    const float* bhh1 = (const float*)d_in[8];
    const float* Wfc  = (const float*)d_in[9];
    const float* bfc  = (const float*)d_in[10];
    float* out = (float*)d_out;

    char* ws = (char*)d_ws;
    size_t off = 0;
    auto alloc = [&](size_t bytes) -> void* {
        void* p = ws + off;
        off += (bytes + 255) & ~(size_t)255;
        return p;
    };
    bf16_t* Wcat0 = (bf16_t*)alloc((size_t)4096 * LD0 * 2);           // 8.9 MB
    bf16_t* Wcat1 = (bf16_t*)alloc((size_t)4096 * LD1 * 2);           // 16.8 MB
    bf16_t* xbf   = (bf16_t*)alloc((size_t)NB * T_SEQ * FIN * 2);     // 8.4 MB
    bf16_t* h2buf = (bf16_t*)alloc((size_t)NB * T_SEQ * HID * 2);     // 134 MB
    bf16_t* h0s   = (bf16_t*)alloc((size_t)2 * HB * 2);
    bf16_t* h1x   = (bf16_t*)alloc((size_t)2 * HB * 2);
    bf16_t* h1s   = (bf16_t*)alloc((size_t)2 * HB * 2);
    float*  c0    = (float*)alloc((size_t)HB * 4);
    float*  c1    = (float*)alloc((size_t)HB * 4);
    float*  bias0 = (float*)alloc(4096 * 4);
    float*  bias1 = (float*)alloc(4096 * 4);
    bf16_t* Wfcb  = (bf16_t*)alloc((size_t)64 * HID * 2);
    if (off > ws_size) return;

    // Opt in to >64KB dynamic LDS (host-side attribute set; graph-capture safe).
    hipFuncSetAttribute((const void*)lstm_persist,
                        hipFuncAttributeMaxDynamicSharedMemorySize, LDS_BYTES);

    prep_kernel<<<1024, 256, 0, stream>>>(x, Wih0, Whh0, bih0, bhh0,
                                          Wih1, Whh1, bih1, bhh1, Wfc,
                                          Wcat0, Wcat1, xbf, Wfcb,
                                          bias0, bias1, h0s, h1s, c0, c1);

    void* args[] = { (void*)&Wcat0, (void*)&Wcat1, (void*)&bias0, (void*)&bias1,
                     (void*)&xbf, (void*)&h0s, (void*)&h1x, (void*)&h1s,
                     (void*)&c0, (void*)&c1, (void*)&h2buf };
    hipLaunchCooperativeKernel((void*)lstm_persist, dim3(256), dim3(512),
                               args, LDS_BYTES, stream);

    fc_kernel<<<(NB * T_SEQ) / 64, 256, 0, stream>>>(h2buf, Wfcb, bfc, out);
}

// Round 3
// 22006.618 us; speedup vs baseline: 1.4333x; 1.4333x over previous
//
#include <hip/hip_runtime.h>
#include <hip/hip_bf16.h>

typedef __bf16 bf16_t;
typedef bf16_t bf16x8 __attribute__((ext_vector_type(8)));
typedef float f32x4 __attribute__((ext_vector_type(4)));

#define T_SEQ 512
#define NB 128
#define HID 1024
#define FIN 64
#define LD0 1088                 // 64 + 1024
#define LD1 2048                 // 1024 + 1024
#define HB (NB * HID)
#define ST0 1096                 // LDS row stride (elems): 548 dwords = 4*odd -> uniform banks
#define ST1 2056                 // 1028 dwords = 4*odd
#define NBLK 192                 // 64 layer0 + 128 layer1
#define LDS_BYTES (64 * ST0 * 2) // 140288 B

__device__ __forceinline__ float sigm_f(float x) { return 1.0f / (1.0f + __expf(-x)); }
__device__ __forceinline__ float tanh_f(float x) { return 2.0f * sigm_f(2.0f * x) - 1.0f; }

__global__ __launch_bounds__(256) void prep_kernel(
    const float* __restrict__ x,
    const float* __restrict__ Wih0, const float* __restrict__ Whh0,
    const float* __restrict__ bih0, const float* __restrict__ bhh0,
    const float* __restrict__ Wih1, const float* __restrict__ Whh1,
    const float* __restrict__ bih1, const float* __restrict__ bhh1,
    const float* __restrict__ Wfc,
    bf16_t* __restrict__ Wcat0, bf16_t* __restrict__ Wcat1,
    bf16_t* __restrict__ xbf, bf16_t* __restrict__ Wfcb,
    float* __restrict__ bias0, float* __restrict__ bias1,
    bf16_t* __restrict__ h0s, bf16_t* __restrict__ h1s,
    float* __restrict__ c0, float* __restrict__ c1,
    unsigned* __restrict__ barrier_cnt)
{
    const unsigned stride = gridDim.x * blockDim.x;
    const unsigned i0 = blockIdx.x * blockDim.x + threadIdx.x;
    if (i0 == 0) *barrier_cnt = 0u;

    for (unsigned i = i0; i < 4096u * LD1; i += stride) {
        unsigned m = i >> 11, kk = i & 2047u;
        float v = (kk < HID) ? Wih1[m * HID + kk] : Whh1[m * HID + (kk - HID)];
        Wcat1[i] = (bf16_t)v;
    }
    for (unsigned i = i0; i < 4096u * LD0; i += stride) {
        unsigned m = i / LD0, kk = i - m * LD0;
        float v = (kk < FIN) ? Wih0[m * FIN + kk] : Whh0[m * HID + (kk - FIN)];
        Wcat0[i] = (bf16_t)v;
    }
    for (unsigned i = i0; i < (unsigned)(NB * T_SEQ * FIN); i += stride)
        xbf[i] = (bf16_t)x[i];
    for (unsigned i = i0; i < 64u * HID; i += stride)
        Wfcb[i] = (bf16_t)Wfc[i];
    for (unsigned i = i0; i < 2u * HB; i += stride) {
        h0s[i] = (bf16_t)0.0f; h1s[i] = (bf16_t)0.0f;
    }
    for (unsigned i = i0; i < (unsigned)HB; i += stride) { c0[i] = 0.0f; c1[i] = 0.0f; }
    for (unsigned i = i0; i < 4096u; i += stride) {
        bias0[i] = bih0[i] + bhh0[i];
        bias1[i] = bih1[i] + bhh1[i];
    }
}

// Persistent kernel, 192 blocks x 512 threads, 1 block/CU (LDS-capped), cooperative
// launch for guaranteed co-residency but with a HAND-ROLLED barrier (grid.sync is
// ~60us/call on gfx950 -- measured round 2).
// Blocks 0..63: layer0, 64 gate-rows (16 hidden x 4 gates), full 128 batch, K=1088.
// Blocks 64..191: layer1, 32 gate-rows (8 hidden x 4 gates), full 128 batch, K=2048.
// Weight rows in LDS ordered u*4+gate so MFMA C-layout makes the cell update lane-local.
// Pipeline interval k: L0 computes t=k, L1 computes t=k-1; one barrier per interval.
__global__ __launch_bounds__(512) void lstm_persist(
    const bf16_t* __restrict__ Wcat0, const bf16_t* __restrict__ Wcat1,
    const float* __restrict__ bias0, const float* __restrict__ bias1,
    const bf16_t* __restrict__ xbf,
    bf16_t* __restrict__ h0s,   // [2][NB][HID] layer0 h ping-pong (also layer1's input)
    bf16_t* __restrict__ h1s,   // [2][NB][HID] layer1 h ping-pong
    float* __restrict__ c0, float* __restrict__ c1,   // [HID][NB] fp32
    bf16_t* __restrict__ h2buf, // [NB][T][HID] layer1 h history for final FC
    unsigned* __restrict__ cnt) // monotonic barrier counter
{
    extern __shared__ bf16_t Wl[];
    const int b = blockIdx.x;
    const int tid = threadIdx.x;
    const int layer = (b >= 64);

    // ---- one-time weight gather into LDS ----
    if (!layer) {
        const int g0 = b;
        for (int c = tid; c < 64 * (LD0 / 8); c += 512) {
            int r = c / (LD0 / 8), off = (c % (LD0 / 8)) * 8;
            int u = r >> 2, gate = r & 3;
            *(bf16x8*)(Wl + r * ST0 + off) =
                *(const bf16x8*)(Wcat0 + (size_t)(gate * HID + g0 * 16 + u) * LD0 + off);
        }
    } else {
        const int g1 = b - 64;
        for (int c = tid; c < 32 * (LD1 / 8); c += 512) {
            int r = c >> 8, off = (c & 255) * 8;
            int u = r >> 2, gate = r & 3;
            *(bf16x8*)(Wl + r * ST1 + off) =
                *(const bf16x8*)(Wcat1 + (size_t)(gate * HID + g1 * 8 + u) * LD1 + off);
        }
    }
    __syncthreads();

    const int wv = tid >> 6;
    const int lane = tid & 63;
    const int q = lane >> 4;
    const int l = lane & 15;

    for (int k = 0; k <= T_SEQ; ++k) {
        if (!layer) {
            const int t = k;
            if (t < T_SEQ) {
                const int g0 = b;
                const int mt = wv >> 1, nt = wv & 1;   // 4 M-tiles x 2 N-tiles(64 batch)
                const int n0 = nt * 64;
                const bf16_t* ar = Wl + (mt * 16 + l) * ST0 + q * 8;
                const bf16_t* hr = h0s + (size_t)(k & 1) * HB;
                f32x4 acc[4] = {{0.f,0.f,0.f,0.f},{0.f,0.f,0.f,0.f},{0.f,0.f,0.f,0.f},{0.f,0.f,0.f,0.f}};

                const bf16_t* xp[4]; const bf16_t* hp[4];
#pragma unroll
                for (int s = 0; s < 4; ++s) {
                    int n = n0 + s * 16 + l;
                    xp[s] = xbf + ((size_t)n * T_SEQ + t) * FIN + q * 8;
                    hp[s] = hr + (size_t)n * HID + q * 8;
                }
#pragma unroll
                for (int p = 0; p < 2; ++p) {
                    bf16x8 av = *(const bf16x8*)(ar + p * 32);
#pragma unroll
                    for (int s = 0; s < 4; ++s)
                        acc[s] = __builtin_amdgcn_mfma_f32_16x16x32_bf16(av, *(const bf16x8*)(xp[s] + p * 32), acc[s], 0, 0, 0);
                }
#pragma unroll 4
                for (int p = 0; p < 32; ++p) {
                    bf16x8 av = *(const bf16x8*)(ar + FIN + p * 32);
#pragma unroll
                    for (int s = 0; s < 4; ++s)
                        acc[s] = __builtin_amdgcn_mfma_f32_16x16x32_bf16(av, *(const bf16x8*)(hp[s] + p * 32), acc[s], 0, 0, 0);
                }
                const int j = g0 * 16 + mt * 4 + q;
                const float bi = bias0[j], bff = bias0[HID + j],
                            bg = bias0[2 * HID + j], bo = bias0[3 * HID + j];
                bf16_t* hw = h0s + (size_t)((k + 1) & 1) * HB;
#pragma unroll
                for (int s = 0; s < 4; ++s) {
                    int n = n0 + s * 16 + l;
                    float iv = sigm_f(acc[s][0] + bi);
                    float fv = sigm_f(acc[s][1] + bff);
                    float gv = tanh_f(acc[s][2] + bg);
                    float ov = sigm_f(acc[s][3] + bo);
                    size_t ci = (size_t)j * NB + n;
                    float cn = fv * c0[ci] + iv * gv;
                    c0[ci] = cn;
                    hw[(size_t)n * HID + j] = (bf16_t)(ov * tanh_f(cn));
                }
            }
        } else {
            const int t = k - 1;
            if (t >= 0) {
                const int g1 = b - 64;
                const int mt = wv >> 2, nt = wv & 3;   // 2 M-tiles x 4 N-tiles(32 batch)
                const int n0 = nt * 32;
                const bf16_t* ar = Wl + (mt * 16 + l) * ST1 + q * 8;
                const bf16_t* xr = h0s + (size_t)(k & 1) * HB;  // L0 output at t
                const bf16_t* hr = h1s + (size_t)(t & 1) * HB;
                f32x4 acc[2] = {{0.f,0.f,0.f,0.f},{0.f,0.f,0.f,0.f}};

                const bf16_t* xp[2]; const bf16_t* hp[2];
#pragma unroll
                for (int s = 0; s < 2; ++s) {
                    int n = n0 + s * 16 + l;
                    xp[s] = xr + (size_t)n * HID + q * 8;
                    hp[s] = hr + (size_t)n * HID + q * 8;
                }
#pragma unroll 4
                for (int p = 0; p < 32; ++p) {
                    bf16x8 av = *(const bf16x8*)(ar + p * 32);
                    acc[0] = __builtin_amdgcn_mfma_f32_16x16x32_bf16(av, *(const bf16x8*)(xp[0] + p * 32), acc[0], 0, 0, 0);
                    acc[1] = __builtin_amdgcn_mfma_f32_16x16x32_bf16(av, *(const bf16x8*)(xp[1] + p * 32), acc[1], 0, 0, 0);
                }
#pragma unroll 4
                for (int p = 0; p < 32; ++p) {
                    bf16x8 av = *(const bf16x8*)(ar + HID + p * 32);
                    acc[0] = __builtin_amdgcn_mfma_f32_16x16x32_bf16(av, *(const bf16x8*)(hp[0] + p * 32), acc[0], 0, 0, 0);
                    acc[1] = __builtin_amdgcn_mfma_f32_16x16x32_bf16(av, *(const bf16x8*)(hp[1] + p * 32), acc[1], 0, 0, 0);
                }
                const int j = g1 * 8 + mt * 4 + q;
                const float bi = bias1[j], bff = bias1[HID + j],
                            bg = bias1[2 * HID + j], bo = bias1[3 * HID + j];
                bf16_t* hw = h1s + (size_t)((t + 1) & 1) * HB;
#pragma unroll
                for (int s = 0; s < 2; ++s) {
                    int n = n0 + s * 16 + l;
                    float iv = sigm_f(acc[s][0] + bi);
                    float fv = sigm_f(acc[s][1] + bff);
                    float gv = tanh_f(acc[s][2] + bg);
                    float ov = sigm_f(acc[s][3] + bo);
                    size_t ci = (size_t)j * NB + n;
                    float cn = fv * c1[ci] + iv * gv;
                    c1[ci] = cn;
                    bf16_t hv = (bf16_t)(ov * tanh_f(cn));
                    hw[(size_t)n * HID + j] = hv;
                    h2buf[((size_t)n * T_SEQ + t) * HID + j] = hv;
                }
            }
        }

        // ---- fast grid barrier (monotonic counter; no grid.sync) ----
        if (k < T_SEQ) {
            __syncthreads();               // all block stores issued & waited (vmcnt 0)
            if (tid == 0) {
                __hip_atomic_fetch_add(cnt, 1u, __ATOMIC_RELEASE, __HIP_MEMORY_SCOPE_AGENT);
                const unsigned target = (unsigned)NBLK * (unsigned)(k + 1);
                while (__hip_atomic_load(cnt, __ATOMIC_RELAXED, __HIP_MEMORY_SCOPE_AGENT) < target)
                    __builtin_amdgcn_s_sleep(2);
                __builtin_amdgcn_fence(__ATOMIC_ACQUIRE, "agent");  // inv L1/L2 -> see remote h
            }
            __syncthreads();
        }
    }
}

// Final FC: out[m][o] = h2[m][:] @ Wfc[o][:] + bfc[o], m = n*T + t (65536 rows).
__global__ __launch_bounds__(256) void fc_kernel(
    const bf16_t* __restrict__ h2buf, const bf16_t* __restrict__ Wfcb,
    const float* __restrict__ bfc, float* __restrict__ out)
{
    const int tid = threadIdx.x, wv = tid >> 6, lane = tid & 63;
    const int q = lane >> 4, l = lane & 15;
    const int m0 = blockIdx.x * 64 + wv * 16;
    const bf16_t* arow = h2buf + (size_t)(m0 + l) * HID + q * 8;
    const bf16_t* brow = Wfcb + (size_t)l * HID + q * 8;
    f32x4 acc[4] = {{0.f,0.f,0.f,0.f},{0.f,0.f,0.f,0.f},{0.f,0.f,0.f,0.f},{0.f,0.f,0.f,0.f}};
#pragma unroll 4
    for (int p = 0; p < 32; ++p) {
        bf16x8 av = *(const bf16x8*)(arow + p * 32);
#pragma unroll
        for (int ntile = 0; ntile < 4; ++ntile) {
            bf16x8 bv = *(const bf16x8*)(brow + (size_t)ntile * 16 * HID + p * 32);
            acc[ntile] = __builtin_amdgcn_mfma_f32_16x16x32_bf16(av, bv, acc[ntile], 0, 0, 0);
        }
    }
#pragma unroll
    for (int ntile = 0; ntile < 4; ++ntile) {
        float bv = bfc[ntile * 16 + l];
#pragma unroll
        for (int r = 0; r < 4; ++r)
            out[(size_t)(m0 + q * 4 + r) * 64 + ntile * 16 + l] = acc[ntile][r] + bv;
    }
}

extern "C" void kernel_launch(void* const* d_in, const int* in_sizes, int n_in,
                              void* d_out, int out_size, void* d_ws, size_t ws_size,
                              hipStream_t stream)
{
    const float* x    = (const float*)d_in[0];
    const float* Wih0 = (const float*)d_in[1];
    const float* Whh0 = (const float*)d_in[2];
    const float* bih0 = (const float*)d_in[3];
    const float* bhh0 = (const float*)d_in[4];
    const float* Wih1 = (const float*)d_in[5];
    const float* Whh1 = (const float*)d_in[6];
    const float* bih1 = (const float*)d_in[7];
    const float* bhh1 = (const float*)d_in[8];
    const float* Wfc  = (const float*)d_in[9];
    const float* bfc  = (const float*)d_in[10];
    float* out = (float*)d_out;

    char* ws = (char*)d_ws;
    size_t off = 0;
    auto alloc = [&](size_t bytes) -> void* {
        void* p = ws + off;
        off += (bytes + 255) & ~(size_t)255;
        return p;
    };
    bf16_t* Wcat0 = (bf16_t*)alloc((size_t)4096 * LD0 * 2);
    bf16_t* Wcat1 = (bf16_t*)alloc((size_t)4096 * LD1 * 2);
    bf16_t* xbf   = (bf16_t*)alloc((size_t)NB * T_SEQ * FIN * 2);
    bf16_t* h2buf = (bf16_t*)alloc((size_t)NB * T_SEQ * HID * 2);
    bf16_t* h0s   = (bf16_t*)alloc((size_t)2 * HB * 2);
    bf16_t* h1s   = (bf16_t*)alloc((size_t)2 * HB * 2);
    float*  c0    = (float*)alloc((size_t)HB * 4);
    float*  c1    = (float*)alloc((size_t)HB * 4);
    float*  bias0 = (float*)alloc(4096 * 4);
    float*  bias1 = (float*)alloc(4096 * 4);
    bf16_t* Wfcb  = (bf16_t*)alloc((size_t)64 * HID * 2);
    unsigned* cntp = (unsigned*)alloc(256);
    if (off > ws_size) return;

    hipFuncSetAttribute((const void*)lstm_persist,
                        hipFuncAttributeMaxDynamicSharedMemorySize, LDS_BYTES);

    prep_kernel<<<1024, 256, 0, stream>>>(x, Wih0, Whh0, bih0, bhh0,
                                          Wih1, Whh1, bih1, bhh1, Wfc,
                                          Wcat0, Wcat1, xbf, Wfcb,
                                          bias0, bias1, h0s, h1s, c0, c1, cntp);

    void* args[] = { (void*)&Wcat0, (void*)&Wcat1, (void*)&bias0, (void*)&bias1,
                     (void*)&xbf, (void*)&h0s, (void*)&h1s,
                     (void*)&c0, (void*)&c1, (void*)&h2buf, (void*)&cntp };
    hipLaunchCooperativeKernel((void*)lstm_persist, dim3(NBLK), dim3(512),
                               args, LDS_BYTES, stream);

    fc_kernel<<<(NB * T_SEQ) / 64, 256, 0, stream>>>(h2buf, Wfcb, bfc, out);
}

// Round 4
// 18639.586 us; speedup vs baseline: 1.6922x; 1.1806x over previous
//
#include <hip/hip_runtime.h>
#include <hip/hip_bf16.h>

typedef __bf16 bf16_t;
typedef bf16_t bf16x8 __attribute__((ext_vector_type(8)));
typedef float f32x4 __attribute__((ext_vector_type(4)));
typedef unsigned long long u64;

#define T_SEQ 512
#define NB 128
#define HID 1024
#define FIN 64
#define LD0 1088                 // 64 + 1024
#define LD1 2048                 // 1024 + 1024
#define HB (NB * HID)
#define ST0 1096                 // LDS row stride (elems), 548 dwords = 4*odd
#define ST1 2056                 // 1028 dwords = 4*odd
#define NBLK 192                 // 64 layer0 + 128 layer1
#define LDS_BYTES (64 * ST0 * 2 + 128 * 16 * 2)  // 144384: weights + h-stage

__device__ __forceinline__ float sigm_f(float x) { return 1.0f / (1.0f + __expf(-x)); }
__device__ __forceinline__ float tanh_f(float x) { return 2.0f * sigm_f(2.0f * x) - 1.0f; }

// Coherent (IF-level, cross-XCD) 16B load as 2 relaxed agent-scope atomic u64s.
// No fences: relaxed atomics bypass L1/L2 (sc0 sc1) and are served at the
// Infinity Cache, the device coherence point.
__device__ __forceinline__ bf16x8 ldc16(const bf16_t* p) {
    const u64* q = (const u64*)p;
    union { u64 u[2]; bf16x8 v; } r;
    r.u[0] = __hip_atomic_load(q,     __ATOMIC_RELAXED, __HIP_MEMORY_SCOPE_AGENT);
    r.u[1] = __hip_atomic_load(q + 1, __ATOMIC_RELAXED, __HIP_MEMORY_SCOPE_AGENT);
    return r.v;
}
__device__ __forceinline__ void stc64(u64* p, u64 v) {
    __hip_atomic_store(p, v, __ATOMIC_RELAXED, __HIP_MEMORY_SCOPE_AGENT);
}
__device__ __forceinline__ unsigned ldcnt(const unsigned* p) {
    return __hip_atomic_load(p, __ATOMIC_RELAXED, __HIP_MEMORY_SCOPE_AGENT);
}

__global__ __launch_bounds__(256) void prep_kernel(
    const float* __restrict__ x,
    const float* __restrict__ Wih0, const float* __restrict__ Whh0,
    const float* __restrict__ bih0, const float* __restrict__ bhh0,
    const float* __restrict__ Wih1, const float* __restrict__ Whh1,
    const float* __restrict__ bih1, const float* __restrict__ bhh1,
    const float* __restrict__ Wfc,
    bf16_t* __restrict__ Wcat0, bf16_t* __restrict__ Wcat1,
    bf16_t* __restrict__ xbf, bf16_t* __restrict__ Wfcb,
    float* __restrict__ bias0, float* __restrict__ bias1,
    bf16_t* __restrict__ h0s, bf16_t* __restrict__ h1s,
    float* __restrict__ c0, float* __restrict__ c1,
    unsigned* __restrict__ cnt)
{
    const unsigned stride = gridDim.x * blockDim.x;
    const unsigned i0 = blockIdx.x * blockDim.x + threadIdx.x;
    if (i0 < 64) cnt[i0] = 0u;

    for (unsigned i = i0; i < 4096u * LD1; i += stride) {
        unsigned m = i >> 11, kk = i & 2047u;
        float v = (kk < HID) ? Wih1[m * HID + kk] : Whh1[m * HID + (kk - HID)];
        Wcat1[i] = (bf16_t)v;
    }
    for (unsigned i = i0; i < 4096u * LD0; i += stride) {
        unsigned m = i / LD0, kk = i - m * LD0;
        float v = (kk < FIN) ? Wih0[m * FIN + kk] : Whh0[m * HID + (kk - FIN)];
        Wcat0[i] = (bf16_t)v;
    }
    for (unsigned i = i0; i < (unsigned)(NB * T_SEQ * FIN); i += stride)
        xbf[i] = (bf16_t)x[i];
    for (unsigned i = i0; i < 64u * HID; i += stride)
        Wfcb[i] = (bf16_t)Wfc[i];
    for (unsigned i = i0; i < 4u * HB; i += stride) h0s[i] = (bf16_t)0.0f;
    for (unsigned i = i0; i < 2u * HB; i += stride) h1s[i] = (bf16_t)0.0f;
    for (unsigned i = i0; i < (unsigned)HB; i += stride) { c0[i] = 0.0f; c1[i] = 0.0f; }
    for (unsigned i = i0; i < 4096u; i += stride) {
        bias0[i] = bih0[i] + bhh0[i];
        bias1[i] = bih1[i] + bhh1[i];
    }
}

// Persistent cooperative kernel, 192 blocks x 512 threads, 1 block/CU.
// Blocks 0..63 = layer0 (64 gate-rows, K=1088); 64..191 = layer1 (32 gate-rows, K=2048).
// Weights LDS-resident, rows ordered u*4+gate -> lane-local cell update.
// Wave w = batch slice [w*16, w*16+16): each block reads h exactly ONCE (no wave dup).
// Sync: per-group monotonic counters, relaxed agent atomics only (NO fences in loop);
// all cross-block h traffic via write-through IF-coherent atomics (ldc16/stc64).
// h0 ring depth 4 decouples the two groups (L0 can lead L1 by up to 3 steps).
__global__ __launch_bounds__(512) void lstm_persist(
    const bf16_t* __restrict__ Wcat0, const bf16_t* __restrict__ Wcat1,
    const float* __restrict__ bias0, const float* __restrict__ bias1,
    const bf16_t* __restrict__ xbf,
    bf16_t* __restrict__ h0s,   // [4][NB][HID] layer0 h ring
    bf16_t* __restrict__ h1s,   // [2][NB][HID] layer1 h ping-pong
    float* __restrict__ c0, float* __restrict__ c1,   // [HID][NB] fp32, block-private
    bf16_t* __restrict__ h2buf, // [NB][T][HID] layer1 h history for final FC
    unsigned* __restrict__ cnt) // cnt[0]=L0 counter, cnt[32]=L1 counter
{
    extern __shared__ bf16_t Wl[];
    const int b = blockIdx.x;
    const int tid = threadIdx.x;
    const int layer = (b >= 64);
    unsigned* cnt0 = cnt;
    unsigned* cnt1 = cnt + 32;

    // ---- one-time weight gather into LDS ----
    bf16_t* stage;
    if (!layer) {
        const int g0 = b;
        for (int c = tid; c < 64 * (LD0 / 8); c += 512) {
            int r = c / (LD0 / 8), off = (c % (LD0 / 8)) * 8;
            int u = r >> 2, gate = r & 3;
            *(bf16x8*)(Wl + r * ST0 + off) =
                *(const bf16x8*)(Wcat0 + (size_t)(gate * HID + g0 * 16 + u) * LD0 + off);
        }
        stage = Wl + 64 * ST0;
    } else {
        const int g1 = b - 64;
        for (int c = tid; c < 32 * (LD1 / 8); c += 512) {
            int r = c >> 8, off = (c & 255) * 8;
            int u = r >> 2, gate = r & 3;
            *(bf16x8*)(Wl + r * ST1 + off) =
                *(const bf16x8*)(Wcat1 + (size_t)(gate * HID + g1 * 8 + u) * LD1 + off);
        }
        stage = Wl + 32 * ST1;
    }
    __syncthreads();

    const int wv = tid >> 6;
    const int lane = tid & 63;
    const int q = lane >> 4;
    const int l = lane & 15;
    const int nn = wv * 16 + l;    // this lane's batch row (wave = 16-batch slice)

    for (int t = 0; t < T_SEQ; ++t) {
        // ---- wait (relaxed polls only; no fences) ----
        if (tid == 0) {
            if (!layer) {
                const unsigned tgt0 = 64u * (unsigned)t;          // own chain: all did t-1
                while (ldcnt(cnt0) < tgt0) __builtin_amdgcn_s_sleep(1);
                if (t >= 4) {
                    const unsigned tgt1 = 128u * (unsigned)(t - 3); // ring slot reusable
                    while (ldcnt(cnt1) < tgt1) __builtin_amdgcn_s_sleep(1);
                }
            } else {
                const unsigned tgt1 = 128u * (unsigned)t;         // own chain
                while (ldcnt(cnt1) < tgt1) __builtin_amdgcn_s_sleep(1);
                const unsigned tgt0 = 64u * (unsigned)(t + 1);    // h0[t] fully written
                while (ldcnt(cnt0) < tgt0) __builtin_amdgcn_s_sleep(1);
            }
        }
        __syncthreads();

        if (!layer) {
            const int g0 = b;
            const bf16_t* hr = h0s + (size_t)((t + 3) & 3) * HB;  // slot (t-1)%4
            f32x4 acc[4] = {{0.f,0.f,0.f,0.f},{0.f,0.f,0.f,0.f},{0.f,0.f,0.f,0.f},{0.f,0.f,0.f,0.f}};

            // x contribution (block-private, normal cached loads)
            const bf16_t* xp = xbf + ((size_t)nn * T_SEQ + t) * FIN + q * 8;
#pragma unroll
            for (int p = 0; p < 2; ++p) {
                bf16x8 bv = *(const bf16x8*)(xp + p * 32);
#pragma unroll
                for (int mt = 0; mt < 4; ++mt) {
                    bf16x8 av = *(const bf16x8*)(Wl + (mt * 16 + l) * ST0 + p * 32 + q * 8);
                    acc[mt] = __builtin_amdgcn_mfma_f32_16x16x32_bf16(av, bv, acc[mt], 0, 0, 0);
                }
            }
            // h contribution: coherent loads, 8-deep prefetch ring
            const bf16_t* hp = hr + (size_t)nn * HID + q * 8;
            bf16x8 bb[8];
#pragma unroll
            for (int i = 0; i < 8; ++i) bb[i] = ldc16(hp + i * 32);
#pragma unroll
            for (int p = 0; p < 32; ++p) {
                bf16x8 bv = bb[p & 7];
#pragma unroll
                for (int mt = 0; mt < 4; ++mt) {
                    bf16x8 av = *(const bf16x8*)(Wl + (mt * 16 + l) * ST0 + FIN + p * 32 + q * 8);
                    acc[mt] = __builtin_amdgcn_mfma_f32_16x16x32_bf16(av, bv, acc[mt], 0, 0, 0);
                }
                if (p + 8 < 32) bb[p & 7] = ldc16(hp + (p + 8) * 32);
            }
            // lane-local cell update; h staged in LDS for coalesced packed store
#pragma unroll
            for (int mt = 0; mt < 4; ++mt) {
                const int u = mt * 4 + q, j = g0 * 16 + u;
                float iv = sigm_f(acc[mt][0] + bias0[j]);
                float fv = sigm_f(acc[mt][1] + bias0[HID + j]);
                float gv = tanh_f(acc[mt][2] + bias0[2 * HID + j]);
                float ov = sigm_f(acc[mt][3] + bias0[3 * HID + j]);
                const size_t ci = (size_t)j * NB + nn;
                float cn = fv * c0[ci] + iv * gv;
                c0[ci] = cn;
                stage[nn * 16 + u] = (bf16_t)(ov * tanh_f(cn));
            }
            __syncthreads();
            {   // packed write-through store: 4 hidden (8B) per thread, n-coalesced
                const int n = tid >> 2, j4 = (tid & 3) * 4;
                u64 v = *(const u64*)(stage + n * 16 + j4);
                stc64((u64*)(h0s + (size_t)(t & 3) * HB + (size_t)n * HID + g0 * 16 + j4), v);
            }
        } else {
            const int g1 = b - 64;
            const bf16_t* xr = h0s + (size_t)(t & 3) * HB;        // L0 output at t
            const bf16_t* hr = h1s + (size_t)((t + 1) & 1) * HB;  // own h at t-1
            const bf16_t* xp = xr + (size_t)nn * HID + q * 8;
            const bf16_t* hp = hr + (size_t)nn * HID + q * 8;
            f32x4 acc[2] = {{0.f,0.f,0.f,0.f},{0.f,0.f,0.f,0.f}};
            bf16x8 bb[8];
#pragma unroll
            for (int i = 0; i < 8; ++i) bb[i] = ldc16(xp + i * 32);
#pragma unroll
            for (int p = 0; p < 64; ++p) {       // panels 0..31 from h0[t], 32..63 from h1[t-1]
                bf16x8 bv = bb[p & 7];
#pragma unroll
                for (int mt = 0; mt < 2; ++mt) {
                    bf16x8 av = *(const bf16x8*)(Wl + (mt * 16 + l) * ST1 + p * 32 + q * 8);
                    acc[mt] = __builtin_amdgcn_mfma_f32_16x16x32_bf16(av, bv, acc[mt], 0, 0, 0);
                }
                const int pn = p + 8;
                if (pn < 32)      bb[p & 7] = ldc16(xp + pn * 32);
                else if (pn < 64) bb[p & 7] = ldc16(hp + (pn - 32) * 32);
            }
#pragma unroll
            for (int mt = 0; mt < 2; ++mt) {
                const int u = mt * 4 + q, j = g1 * 8 + u;
                float iv = sigm_f(acc[mt][0] + bias1[j]);
                float fv = sigm_f(acc[mt][1] + bias1[HID + j]);
                float gv = tanh_f(acc[mt][2] + bias1[2 * HID + j]);
                float ov = sigm_f(acc[mt][3] + bias1[3 * HID + j]);
                const size_t ci = (size_t)j * NB + nn;
                float cn = fv * c1[ci] + iv * gv;
                c1[ci] = cn;
                stage[nn * 8 + u] = (bf16_t)(ov * tanh_f(cn));
            }
            __syncthreads();
            if (tid < 256) {    // 128 n x 8 hidden = 256 u64 packed stores
                const int n = tid >> 1, j4 = (tid & 1) * 4;
                u64 v = *(const u64*)(stage + n * 8 + j4);
                stc64((u64*)(h1s + (size_t)(t & 1) * HB + (size_t)n * HID + g1 * 8 + j4), v);
                *(u64*)(h2buf + ((size_t)n * T_SEQ + t) * HID + g1 * 8 + j4) = v;  // normal store
            }
        }

        __syncthreads();   // drains vmcnt: all this block's stores are at IF
        if (tid == 0)
            __hip_atomic_fetch_add(layer ? cnt1 : cnt0, 1u,
                                   __ATOMIC_RELAXED, __HIP_MEMORY_SCOPE_AGENT);
    }
}

// Final FC: out[m][o] = h2[m][:] @ Wfc[o][:] + bfc[o], m = n*T + t (65536 rows).
__global__ __launch_bounds__(256) void fc_kernel(
    const bf16_t* __restrict__ h2buf, const bf16_t* __restrict__ Wfcb,
    const float* __restrict__ bfc, float* __restrict__ out)
{
    const int tid = threadIdx.x, wv = tid >> 6, lane = tid & 63;
    const int q = lane >> 4, l = lane & 15;
    const int m0 = blockIdx.x * 64 + wv * 16;
    const bf16_t* arow = h2buf + (size_t)(m0 + l) * HID + q * 8;
    const bf16_t* brow = Wfcb + (size_t)l * HID + q * 8;
    f32x4 acc[4] = {{0.f,0.f,0.f,0.f},{0.f,0.f,0.f,0.f},{0.f,0.f,0.f,0.f},{0.f,0.f,0.f,0.f}};
#pragma unroll 4
    for (int p = 0; p < 32; ++p) {
        bf16x8 av = *(const bf16x8*)(arow + p * 32);
#pragma unroll
        for (int ntile = 0; ntile < 4; ++ntile) {
            bf16x8 bv = *(const bf16x8*)(brow + (size_t)ntile * 16 * HID + p * 32);
            acc[ntile] = __builtin_amdgcn_mfma_f32_16x16x32_bf16(av, bv, acc[ntile], 0, 0, 0);
        }
    }
#pragma unroll
    for (int ntile = 0; ntile < 4; ++ntile) {
        float bv = bfc[ntile * 16 + l];
#pragma unroll
        for (int r = 0; r < 4; ++r)
            out[(size_t)(m0 + q * 4 + r) * 64 + ntile * 16 + l] = acc[ntile][r] + bv;
    }
}

extern "C" void kernel_launch(void* const* d_in, const int* in_sizes, int n_in,
                              void* d_out, int out_size, void* d_ws, size_t ws_size,
                              hipStream_t stream)
{
    const float* x    = (const float*)d_in[0];
    const float* Wih0 = (const float*)d_in[1];
    const float* Whh0 = (const float*)d_in[2];
    const float* bih0 = (const float*)d_in[3];
    const float* bhh0 = (const float*)d_in[4];
    const float* Wih1 = (const float*)d_in[5];
    const float* Whh1 = (const float*)d_in[6];
    const float* bih1 = (const float*)d_in[7];
    const float* bhh1 = (const float*)d_in[8];
    const float* Wfc  = (const float*)d_in[9];
    const float* bfc  = (const float*)d_in[10];
    float* out = (float*)d_out;

    char* ws = (char*)d_ws;
    size_t off = 0;
    auto alloc = [&](size_t bytes) -> void* {
        void* p = ws + off;
        off += (bytes + 255) & ~(size_t)255;
        return p;
    };
    bf16_t* Wcat0 = (bf16_t*)alloc((size_t)4096 * LD0 * 2);
    bf16_t* Wcat1 = (bf16_t*)alloc((size_t)4096 * LD1 * 2);
    bf16_t* xbf   = (bf16_t*)alloc((size_t)NB * T_SEQ * FIN * 2);
    bf16_t* h2buf = (bf16_t*)alloc((size_t)NB * T_SEQ * HID * 2);
    bf16_t* h0s   = (bf16_t*)alloc((size_t)4 * HB * 2);
    bf16_t* h1s   = (bf16_t*)alloc((size_t)2 * HB * 2);
    float*  c0    = (float*)alloc((size_t)HB * 4);
    float*  c1    = (float*)alloc((size_t)HB * 4);
    float*  bias0 = (float*)alloc(4096 * 4);
    float*  bias1 = (float*)alloc(4096 * 4);
    bf16_t* Wfcb  = (bf16_t*)alloc((size_t)64 * HID * 2);
    unsigned* cntp = (unsigned*)alloc(256);
    if (off > ws_size) return;

    hipFuncSetAttribute((const void*)lstm_persist,
                        hipFuncAttributeMaxDynamicSharedMemorySize, LDS_BYTES);

    prep_kernel<<<1024, 256, 0, stream>>>(x, Wih0, Whh0, bih0, bhh0,
                                          Wih1, Whh1, bih1, bhh1, Wfc,
                                          Wcat0, Wcat1, xbf, Wfcb,
                                          bias0, bias1, h0s, h1s, c0, c1, cntp);

    void* args[] = { (void*)&Wcat0, (void*)&Wcat1, (void*)&bias0, (void*)&bias1,
                     (void*)&xbf, (void*)&h0s, (void*)&h1s,
                     (void*)&c0, (void*)&c1, (void*)&h2buf, (void*)&cntp };
    hipLaunchCooperativeKernel((void*)lstm_persist, dim3(NBLK), dim3(512),
                               args, LDS_BYTES, stream);

    fc_kernel<<<(NB * T_SEQ) / 64, 256, 0, stream>>>(h2buf, Wfcb, bfc, out);
}

// Round 5
// 18477.019 us; speedup vs baseline: 1.7071x; 1.0088x over previous
//
#include <hip/hip_runtime.h>
#include <hip/hip_bf16.h>

typedef __bf16 bf16_t;
typedef bf16_t bf16x8 __attribute__((ext_vector_type(8)));
typedef float f32x4 __attribute__((ext_vector_type(4)));
typedef unsigned long long u64;

#define T_SEQ 512
#define NB 128
#define HID 1024
#define FIN 64
#define LD0 1088                 // 64 + 1024
#define LD1 2048                 // 1024 + 1024
#define HB (NB * HID)            // 131072 elems per h snapshot (256 KB bf16)
#define ST0 1096                 // LDS weight row stride (elems)
#define ST1 2056
#define NBLK 192                 // 64 L0 + 128 L1
#define DM 16                    // master ring depth (eviction-coherence margin)
#define DX 4                     // per-XCD staged ring depth
#define UNITS 16384              // 16B units per h snapshot
#define LDS_BYTES (64 * ST0 * 2 + 4096)   // weights + stage buffer

// sync[] layout (unsigned units; each counter on its own 256B line)
#define C0i 0                    // L0 completions (monotonic)
#define C1i 64                   // L1 completions
#define SC0i(x) (128 + (x)*64)   // per-XCD xh0 stage completions
#define SC1i(x) (768 + (x)*64)   // per-XCD xh1 stage completions
#define XREGi(x) (1536 + (x)*64) // per-XCD L0-block registration
#define REGCi 2048               // global registration
#define SYNC_N 2112

__device__ __forceinline__ float sigm_f(float x) { return 1.0f / (1.0f + __expf(-x)); }
__device__ __forceinline__ float tanh_f(float x) { return 2.0f * sigm_f(2.0f * x) - 1.0f; }

__device__ __forceinline__ unsigned ldcnt(const unsigned* p) {
    return __hip_atomic_load(p, __ATOMIC_RELAXED, __HIP_MEMORY_SCOPE_AGENT);
}
__device__ __forceinline__ void stw64(u64* p, u64 v) {  // write-through to IF
    __hip_atomic_store(p, v, __ATOMIC_RELAXED, __HIP_MEMORY_SCOPE_AGENT);
}

// Fragment-swizzled h layout: 16B unit index = (panel*8 + wv)*64 + lane,
// holding h[n = wv*16 + (lane&15)][k = panel*32 + (lane>>4)*8 .. +8].
// Consumers load one wave-contiguous 1KB fragment per MFMA panel.

__global__ __launch_bounds__(256) void prep_kernel(
    const float* __restrict__ x,
    const float* __restrict__ Wih0, const float* __restrict__ Whh0,
    const float* __restrict__ bih0, const float* __restrict__ bhh0,
    const float* __restrict__ Wih1, const float* __restrict__ Whh1,
    const float* __restrict__ bih1, const float* __restrict__ bhh1,
    const float* __restrict__ Wfc,
    bf16_t* __restrict__ Wcat0, bf16_t* __restrict__ Wcat1,
    bf16_t* __restrict__ xswz, bf16_t* __restrict__ Wfcb,
    float* __restrict__ bias0, float* __restrict__ bias1,
    bf16_t* __restrict__ mh0, bf16_t* __restrict__ mh1,
    bf16_t* __restrict__ xh0, bf16_t* __restrict__ xh1,
    float* __restrict__ c0, float* __restrict__ c1,
    unsigned* __restrict__ sync)
{
    const unsigned stride = gridDim.x * blockDim.x;
    const unsigned i0 = blockIdx.x * blockDim.x + threadIdx.x;

    for (unsigned i = i0; i < SYNC_N; i += stride) sync[i] = 0u;

    for (unsigned i = i0; i < 4096u * LD1; i += stride) {
        unsigned m = i >> 11, kk = i & 2047u;
        float v = (kk < HID) ? Wih1[m * HID + kk] : Whh1[m * HID + (kk - HID)];
        Wcat1[i] = (bf16_t)v;
    }
    for (unsigned i = i0; i < 4096u * LD0; i += stride) {
        unsigned m = i / LD0, kk = i - m * LD0;
        float v = (kk < FIN) ? Wih0[m * FIN + kk] : Whh0[m * HID + (kk - FIN)];
        Wcat0[i] = (bf16_t)v;
    }
    // x into fragment-swizzled layout: elem i -> (unit, e)
    for (unsigned i = i0; i < 4194304u; i += stride) {   // 128*512*64
        unsigned e = i & 7u, unit = i >> 3;
        unsigned lane = unit & 63u, g = unit >> 6;
        unsigned wvv = g & 7u, pt = g >> 3;              // pt = t*2 + p
        unsigned p = pt & 1u, t = pt >> 1;
        unsigned n = wvv * 16u + (lane & 15u);
        unsigned k = p * 32u + (lane >> 4) * 8u + e;
        xswz[i] = (bf16_t)x[((size_t)n * T_SEQ + t) * FIN + k];
    }
    for (unsigned i = i0; i < 64u * HID; i += stride)
        Wfcb[i] = (bf16_t)Wfc[i];
    for (unsigned i = i0; i < (unsigned)(DM * HB); i += stride) {
        mh0[i] = (bf16_t)0.0f; mh1[i] = (bf16_t)0.0f;
    }
    for (unsigned i = i0; i < (unsigned)(8 * DX * HB); i += stride) {
        xh0[i] = (bf16_t)0.0f; xh1[i] = (bf16_t)0.0f;
    }
    for (unsigned i = i0; i < (unsigned)HB; i += stride) { c0[i] = 0.0f; c1[i] = 0.0f; }
    for (unsigned i = i0; i < 4096u; i += stride) {
        bias0[i] = bih0[i] + bhh0[i];
        bias1[i] = bih1[i] + bhh1[i];
    }
}

// Persistent cooperative kernel: 192 blocks x 512 threads, 1 block/CU.
// Blocks 0..63 = L0 (64 gate-rows, K=1088); 64..191 = L1 (32 gate-rows, K=2048).
// h transport: producers -> master (IF, swizzled, atomic write-through)
//            -> per-physical-XCD relay memcpy (normal ld/st through own L2)
//            -> consumers (normal coalesced loads from own XCD's L2).
// No fences anywhere; coherence by write-through + capacity-eviction rings.
__global__ __launch_bounds__(512) void lstm_persist(
    const bf16_t* __restrict__ Wcat0, const bf16_t* __restrict__ Wcat1,
    const float* __restrict__ bias0, const float* __restrict__ bias1,
    const bf16_t* __restrict__ xswz,
    bf16_t* __restrict__ mh0,   // [DM][HB] master h0 ring (swizzled)
    bf16_t* __restrict__ mh1,   // [DM][HB] master h1 ring
    bf16_t* __restrict__ xh0,   // [8][DX][HB] per-XCD staged h0
    bf16_t* __restrict__ xh1,   // [8][DX][HB] per-XCD staged h1
    float* __restrict__ c0, float* __restrict__ c1,   // [HID][NB], block-private
    bf16_t* __restrict__ h2buf, // [NB][T][HID] layer1 history for FC
    unsigned* __restrict__ sync)
{
    extern __shared__ bf16_t Wl[];
    __shared__ int sh_xcd, sh_rank, sh_k0;
    const int b = blockIdx.x;
    const int tid = threadIdx.x;
    const int layer = (b >= 64);

    // ---- registration & relay election on PHYSICAL XCD id ----
    if (tid == 0) {
        int xcc;
        asm volatile("s_getreg_b32 %0, hwreg(HW_REG_XCC_ID)" : "=s"(xcc));
        xcc &= 7;
        int rk = -1;
        if (!layer)
            rk = (int)__hip_atomic_fetch_add(&sync[XREGi(xcc)], 1u,
                                             __ATOMIC_RELAXED, __HIP_MEMORY_SCOPE_AGENT);
        __hip_atomic_fetch_add(&sync[REGCi], 1u, __ATOMIC_RELAXED, __HIP_MEMORY_SCOPE_AGENT);
        while (ldcnt(&sync[REGCi]) < (unsigned)NBLK) __builtin_amdgcn_s_sleep(2);
        sh_xcd = xcc; sh_rank = rk;
        sh_k0 = (int)ldcnt(&sync[XREGi(xcc)]);
    }

    // ---- one-time weight gather into LDS (rows ordered u*4+gate) ----
    bf16_t* stage;
    if (!layer) {
        const int g0 = b;
        for (int c = tid; c < 64 * (LD0 / 8); c += 512) {
            int r = c / (LD0 / 8), off = (c % (LD0 / 8)) * 8;
            int u = r >> 2, gate = r & 3;
            *(bf16x8*)(Wl + r * ST0 + off) =
                *(const bf16x8*)(Wcat0 + (size_t)(gate * HID + g0 * 16 + u) * LD0 + off);
        }
        stage = Wl + 64 * ST0;
    } else {
        const int g1 = b - 64;
        for (int c = tid; c < 32 * (LD1 / 8); c += 512) {
            int r = c >> 8, off = (c & 255) * 8;
            int u = r >> 2, gate = r & 3;
            *(bf16x8*)(Wl + r * ST1 + off) =
                *(const bf16x8*)(Wcat1 + (size_t)(gate * HID + g1 * 8 + u) * LD1 + off);
        }
        stage = Wl + 32 * ST1;
    }
    __syncthreads();

    const int myxcd = sh_xcd, rank = sh_rank, K0 = sh_k0;
    const int R0 = K0 < 4 ? K0 : 4;
    const bool use8 = (K0 >= 8);
    const int R1 = use8 ? 4 : R0;
    const bool duty0 = (rank >= 0 && rank < R0);
    const bool duty1 = (rank >= 0) && (use8 ? (rank >= 4 && rank < 8) : (rank < R0));
    int a0 = 0, b0 = 0, a1 = 0, b1 = 0;
    if (duty0) { a0 = rank * UNITS / R0; b0 = (rank + 1) * UNITS / R0; }
    if (duty1) { int rr = use8 ? rank - 4 : rank;
                 a1 = rr * UNITS / R1; b1 = (rr + 1) * UNITS / R1; }

    const int wv = tid >> 6;
    const int lane = tid & 63;
    const int q = lane >> 4;
    const int l = lane & 15;
    const int nn = wv * 16 + l;

    for (int t = 0; t < T_SEQ; ++t) {
        if (!layer) {
            const int g0 = b;
            // wait: xh0[h0[t-1]] staged on my XCD (phase t-1)
            if (tid == 0) {
                const unsigned tgt = (unsigned)R0 * (unsigned)t;
                while (ldcnt(&sync[SC0i(myxcd)]) < tgt) __builtin_amdgcn_s_sleep(2);
            }
            __syncthreads();

            f32x4 acc[4] = {{0.f,0.f,0.f,0.f},{0.f,0.f,0.f,0.f},{0.f,0.f,0.f,0.f},{0.f,0.f,0.f,0.f}};
            // x contribution: 2 fragment panels from xswz[t]
            {
                const bf16_t* X = xswz + (((size_t)t * 2) * 8) * 64 * 8;
#pragma unroll
                for (int p = 0; p < 2; ++p) {
                    bf16x8 bv = *(const bf16x8*)(X + (((size_t)p * 8 + wv) * 64 + lane) * 8);
#pragma unroll
                    for (int mt = 0; mt < 4; ++mt) {
                        bf16x8 av = *(const bf16x8*)(Wl + (mt * 16 + l) * ST0 + p * 32 + q * 8);
                        acc[mt] = __builtin_amdgcn_mfma_f32_16x16x32_bf16(av, bv, acc[mt], 0, 0, 0);
                    }
                }
            }
            // h contribution: 32 fragment panels from XCD-staged h0[t-1]
            {
                const bf16_t* B = xh0 + ((size_t)myxcd * DX + ((t + 3) & 3)) * HB;
                bf16x8 bb[8];
#pragma unroll
                for (int i = 0; i < 8; ++i)
                    bb[i] = *(const bf16x8*)(B + (((size_t)i * 8 + wv) * 64 + lane) * 8);
#pragma unroll
                for (int p = 0; p < 32; ++p) {
                    bf16x8 bv = bb[p & 7];
#pragma unroll
                    for (int mt = 0; mt < 4; ++mt) {
                        bf16x8 av = *(const bf16x8*)(Wl + (mt * 16 + l) * ST0 + FIN + p * 32 + q * 8);
                        acc[mt] = __builtin_amdgcn_mfma_f32_16x16x32_bf16(av, bv, acc[mt], 0, 0, 0);
                    }
                    if (p + 8 < 32)
                        bb[p & 7] = *(const bf16x8*)(B + (((size_t)(p + 8) * 8 + wv) * 64 + lane) * 8);
                }
            }
            // lane-local cell update -> stage
#pragma unroll
            for (int mt = 0; mt < 4; ++mt) {
                const int u = mt * 4 + q, j = g0 * 16 + u;
                float iv = sigm_f(acc[mt][0] + bias0[j]);
                float fv = sigm_f(acc[mt][1] + bias0[HID + j]);
                float gv = tanh_f(acc[mt][2] + bias0[2 * HID + j]);
                float ov = sigm_f(acc[mt][3] + bias0[3 * HID + j]);
                const size_t ci = (size_t)j * NB + nn;
                float cn = fv * c0[ci] + iv * gv;
                c0[ci] = cn;
                stage[nn * 16 + u] = (bf16_t)(ov * tanh_f(cn));
            }
            __syncthreads();
            // master write, fragment-swizzled, write-through atomics
            if (tid < 256) {
                const int n = tid >> 1, half = tid & 1;
                u64 v0 = *(const u64*)(stage + n * 16 + half * 8);
                u64 v1 = *(const u64*)(stage + n * 16 + half * 8 + 4);
                size_t unit = ((size_t)((g0 >> 1) * 8 + (n >> 4))) * 64
                              + ((g0 & 1) * 2 + half) * 16 + (n & 15);
                u64* dst = (u64*)(mh0 + (size_t)(t & 15) * HB) + unit * 2;
                stw64(dst, v0); stw64(dst + 1, v1);
            }
            __syncthreads();   // drain stores (vmcnt 0)
            if (tid == 0)
                __hip_atomic_fetch_add(&sync[C0i], 1u, __ATOMIC_RELAXED, __HIP_MEMORY_SCOPE_AGENT);

            // ---- relay phase t (elected L0 blocks only) ----
            if (duty0 || duty1) {
                if (tid == 0) {
                    while (ldcnt(&sync[C0i]) < 64u * (unsigned)(t + 1)) __builtin_amdgcn_s_sleep(2);
                    if (duty1)
                        while (ldcnt(&sync[C1i]) < 128u * (unsigned)t) __builtin_amdgcn_s_sleep(2);
                }
                __syncthreads();
                if (duty0) {
                    const bf16_t* src = mh0 + (size_t)(t & 15) * HB;
                    bf16_t* dst = xh0 + ((size_t)myxcd * DX + (t & 3)) * HB;
                    for (int i = a0 + tid; i < b0; i += 512)
                        *(bf16x8*)(dst + (size_t)i * 8) = *(const bf16x8*)(src + (size_t)i * 8);
                }
                if (duty1) {
                    const bf16_t* src = mh1 + (size_t)((t + 15) & 15) * HB;
                    bf16_t* dst = xh1 + ((size_t)myxcd * DX + ((t + 3) & 3)) * HB;
                    for (int i = a1 + tid; i < b1; i += 512)
                        *(bf16x8*)(dst + (size_t)i * 8) = *(const bf16x8*)(src + (size_t)i * 8);
                }
                __syncthreads();   // relay stores ack'd in this XCD's L2
                if (tid == 0) {
                    if (duty0)
                        __hip_atomic_fetch_add(&sync[SC0i(myxcd)], 1u, __ATOMIC_RELAXED, __HIP_MEMORY_SCOPE_AGENT);
                    if (duty1)
                        __hip_atomic_fetch_add(&sync[SC1i(myxcd)], 1u, __ATOMIC_RELAXED, __HIP_MEMORY_SCOPE_AGENT);
                }
            }
        } else {
            const int g1 = b - 64;
            // wait: xh0[h0[t]] and xh1[h1[t-1]] staged on my XCD (phase t)
            if (tid == 0) {
                const unsigned tg0 = (unsigned)R0 * (unsigned)(t + 1);
                const unsigned tg1 = (unsigned)R1 * (unsigned)(t + 1);
                while (ldcnt(&sync[SC0i(myxcd)]) < tg0) __builtin_amdgcn_s_sleep(2);
                while (ldcnt(&sync[SC1i(myxcd)]) < tg1) __builtin_amdgcn_s_sleep(2);
            }
            __syncthreads();

            const bf16_t* B0 = xh0 + ((size_t)myxcd * DX + (t & 3)) * HB;        // h0[t]
            const bf16_t* B1 = xh1 + ((size_t)myxcd * DX + ((t + 3) & 3)) * HB;  // h1[t-1]
            f32x4 acc[2] = {{0.f,0.f,0.f,0.f},{0.f,0.f,0.f,0.f}};
            bf16x8 bb[8];
#pragma unroll
            for (int i = 0; i < 8; ++i)
                bb[i] = *(const bf16x8*)(B0 + (((size_t)i * 8 + wv) * 64 + lane) * 8);
#pragma unroll
            for (int p = 0; p < 64; ++p) {   // 0..31 from h0[t], 32..63 from h1[t-1]
                bf16x8 bv = bb[p & 7];
#pragma unroll
                for (int mt = 0; mt < 2; ++mt) {
                    bf16x8 av = *(const bf16x8*)(Wl + (mt * 16 + l) * ST1 + p * 32 + q * 8);
                    acc[mt] = __builtin_amdgcn_mfma_f32_16x16x32_bf16(av, bv, acc[mt], 0, 0, 0);
                }
                const int pn = p + 8;
                if (pn < 32)
                    bb[p & 7] = *(const bf16x8*)(B0 + (((size_t)pn * 8 + wv) * 64 + lane) * 8);
                else if (pn < 64)
                    bb[p & 7] = *(const bf16x8*)(B1 + (((size_t)(pn - 32) * 8 + wv) * 64 + lane) * 8);
            }
#pragma unroll
            for (int mt = 0; mt < 2; ++mt) {
                const int u = mt * 4 + q, j = g1 * 8 + u;
                float iv = sigm_f(acc[mt][0] + bias1[j]);
                float fv = sigm_f(acc[mt][1] + bias1[HID + j]);
                float gv = tanh_f(acc[mt][2] + bias1[2 * HID + j]);
                float ov = sigm_f(acc[mt][3] + bias1[3 * HID + j]);
                const size_t ci = (size_t)j * NB + nn;
                float cn = fv * c1[ci] + iv * gv;
                c1[ci] = cn;
                stage[nn * 8 + u] = (bf16_t)(ov * tanh_f(cn));
            }
            __syncthreads();
            if (tid < 128) {   // master write (swizzled, write-through)
                const int n = tid;
                u64 v0 = *(const u64*)(stage + n * 8);
                u64 v1 = *(const u64*)(stage + n * 8 + 4);
                size_t unit = ((size_t)((g1 >> 2) * 8 + (n >> 4))) * 64
                              + (g1 & 3) * 16 + (n & 15);
                u64* dst = (u64*)(mh1 + (size_t)(t & 15) * HB) + unit * 2;
                stw64(dst, v0); stw64(dst + 1, v1);
            }
            if (tid < 256) {   // h2 history (normal stores; read by fc_kernel)
                const int n = tid >> 1, part = tid & 1;
                *(u64*)(h2buf + ((size_t)n * T_SEQ + t) * HID + g1 * 8 + part * 4) =
                    *(const u64*)(stage + n * 8 + part * 4);
            }
            __syncthreads();   // drain
            if (tid == 0)
                __hip_atomic_fetch_add(&sync[C1i], 1u, __ATOMIC_RELAXED, __HIP_MEMORY_SCOPE_AGENT);
        }
    }
}

// Final FC: out[m][o] = h2[m][:] @ Wfc[o][:] + bfc[o], m = n*T + t.
__global__ __launch_bounds__(256) void fc_kernel(
    const bf16_t* __restrict__ h2buf, const bf16_t* __restrict__ Wfcb,
    const float* __restrict__ bfc, float* __restrict__ out)
{
    const int tid = threadIdx.x, wv = tid >> 6, lane = tid & 63;
    const int q = lane >> 4, l = lane & 15;
    const int m0 = blockIdx.x * 64 + wv * 16;
    const bf16_t* arow = h2buf + (size_t)(m0 + l) * HID + q * 8;
    const bf16_t* brow = Wfcb + (size_t)l * HID + q * 8;
    f32x4 acc[4] = {{0.f,0.f,0.f,0.f},{0.f,0.f,0.f,0.f},{0.f,0.f,0.f,0.f},{0.f,0.f,0.f,0.f}};
#pragma unroll 4
    for (int p = 0; p < 32; ++p) {
        bf16x8 av = *(const bf16x8*)(arow + p * 32);
#pragma unroll
        for (int ntile = 0; ntile < 4; ++ntile) {
            bf16x8 bv = *(const bf16x8*)(brow + (size_t)ntile * 16 * HID + p * 32);
            acc[ntile] = __builtin_amdgcn_mfma_f32_16x16x32_bf16(av, bv, acc[ntile], 0, 0, 0);
        }
    }
#pragma unroll
    for (int ntile = 0; ntile < 4; ++ntile) {
        float bv = bfc[ntile * 16 + l];
#pragma unroll
        for (int r = 0; r < 4; ++r)
            out[(size_t)(m0 + q * 4 + r) * 64 + ntile * 16 + l] = acc[ntile][r] + bv;
    }
}

extern "C" void kernel_launch(void* const* d_in, const int* in_sizes, int n_in,
                              void* d_out, int out_size, void* d_ws, size_t ws_size,
                              hipStream_t stream)
{
    const float* x    = (const float*)d_in[0];
    const float* Wih0 = (const float*)d_in[1];
    const float* Whh0 = (const float*)d_in[2];
    const float* bih0 = (const float*)d_in[3];
    const float* bhh0 = (const float*)d_in[4];
    const float* Wih1 = (const float*)d_in[5];
    const float* Whh1 = (const float*)d_in[6];
    const float* bih1 = (const float*)d_in[7];
    const float* bhh1 = (const float*)d_in[8];
    const float* Wfc  = (const float*)d_in[9];
    const float* bfc  = (const float*)d_in[10];
    float* out = (float*)d_out;

    char* ws = (char*)d_ws;
    size_t off = 0;
    auto alloc = [&](size_t bytes) -> void* {
        void* p = ws + off;
        off += (bytes + 255) & ~(size_t)255;
        return p;
    };
    bf16_t* Wcat0 = (bf16_t*)alloc((size_t)4096 * LD0 * 2);           // 8.9 MB
    bf16_t* Wcat1 = (bf16_t*)alloc((size_t)4096 * LD1 * 2);           // 16.8 MB
    bf16_t* xswz  = (bf16_t*)alloc((size_t)NB * T_SEQ * FIN * 2);     // 8.4 MB
    bf16_t* h2buf = (bf16_t*)alloc((size_t)NB * T_SEQ * HID * 2);     // 134 MB
    bf16_t* mh0   = (bf16_t*)alloc((size_t)DM * HB * 2);              // 4.2 MB
    bf16_t* mh1   = (bf16_t*)alloc((size_t)DM * HB * 2);              // 4.2 MB
    bf16_t* xh0   = (bf16_t*)alloc((size_t)8 * DX * HB * 2);          // 8.4 MB
    bf16_t* xh1   = (bf16_t*)alloc((size_t)8 * DX * HB * 2);          // 8.4 MB
    float*  c0    = (float*)alloc((size_t)HB * 4);
    float*  c1    = (float*)alloc((size_t)HB * 4);
    float*  bias0 = (float*)alloc(4096 * 4);
    float*  bias1 = (float*)alloc(4096 * 4);
    bf16_t* Wfcb  = (bf16_t*)alloc((size_t)64 * HID * 2);
    unsigned* syncp = (unsigned*)alloc(SYNC_N * 4);
    if (off > ws_size) return;

    hipFuncSetAttribute((const void*)lstm_persist,
                        hipFuncAttributeMaxDynamicSharedMemorySize, LDS_BYTES);

    prep_kernel<<<1024, 256, 0, stream>>>(x, Wih0, Whh0, bih0, bhh0,
                                          Wih1, Whh1, bih1, bhh1, Wfc,
                                          Wcat0, Wcat1, xswz, Wfcb,
                                          bias0, bias1, mh0, mh1, xh0, xh1,
                                          c0, c1, syncp);

    void* args[] = { (void*)&Wcat0, (void*)&Wcat1, (void*)&bias0, (void*)&bias1,
                     (void*)&xswz, (void*)&mh0, (void*)&mh1, (void*)&xh0, (void*)&xh1,
                     (void*)&c0, (void*)&c1, (void*)&h2buf, (void*)&syncp };
    hipLaunchCooperativeKernel((void*)lstm_persist, dim3(NBLK), dim3(512),
                               args, LDS_BYTES, stream);

    fc_kernel<<<(NB * T_SEQ) / 64, 256, 0, stream>>>(h2buf, Wfcb, bfc, out);
}

// Round 6
// 6361.015 us; speedup vs baseline: 4.9587x; 2.9047x over previous
//
#include <hip/hip_runtime.h>
#include <hip/hip_bf16.h>

typedef __bf16 bf16_t;
typedef bf16_t bf16x8 __attribute__((ext_vector_type(8)));
typedef float f32x4 __attribute__((ext_vector_type(4)));
typedef unsigned long long u64;

#define T_SEQ 512
#define NB 128
#define HID 1024
#define FIN 64
#define LD0 1088                 // 64 + 1024
#define LD1 2048                 // 1024 + 1024
#define HB (NB * HID)            // 131072 elems = 256 KB per h snapshot
#define ST0 1096                 // LDS weight row stride (elems)
#define ST1 2056
#define NBLK 192                 // 64 L0 + 128 L1
#define DM 32                    // master ring depth (9x L2 turnover at reuse)
#define LDS_BYTES (64 * ST0 * 2 + 4096)   // weights + stage

// sync[]: per-block completion flags (value = steps completed). NO shared
// counters -> no atomic-RMW serialization (the r3/r4/r5 ~16us/interval wall).
#define F0 0      // f0[64]:  L0 block flags
#define F1 64     // f1[128]: L1 block flags
#define SYNC_N 256

__device__ __forceinline__ float sigm_f(float x) { return 1.0f / (1.0f + __expf(-x)); }
__device__ __forceinline__ float tanh_f(float x) { return 2.0f * sigm_f(2.0f * x) - 1.0f; }

__device__ __forceinline__ unsigned ldcnt(const unsigned* p) {
    return __hip_atomic_load(p, __ATOMIC_RELAXED, __HIP_MEMORY_SCOPE_AGENT);
}
__device__ __forceinline__ void stw32(unsigned* p, unsigned v) {   // write-through
    __hip_atomic_store(p, v, __ATOMIC_RELAXED, __HIP_MEMORY_SCOPE_AGENT);
}
__device__ __forceinline__ void stw64(u64* p, u64 v) {
    __hip_atomic_store(p, v, __ATOMIC_RELAXED, __HIP_MEMORY_SCOPE_AGENT);
}

// Fragment-swizzled h layout: 16B unit = (panel*8 + wv)*64 + lane, holding
// h[n = wv*16 + (lane&15)][k = panel*32 + (lane>>4)*8 .. +8]: consumers load
// one wave-contiguous 1KB fragment per MFMA panel (plain coalesced loads).

__global__ __launch_bounds__(256) void prep_kernel(
    const float* __restrict__ x,
    const float* __restrict__ Wih0, const float* __restrict__ Whh0,
    const float* __restrict__ bih0, const float* __restrict__ bhh0,
    const float* __restrict__ Wih1, const float* __restrict__ Whh1,
    const float* __restrict__ bih1, const float* __restrict__ bhh1,
    const float* __restrict__ Wfc,
    bf16_t* __restrict__ Wcat0, bf16_t* __restrict__ Wcat1,
    bf16_t* __restrict__ xswz, bf16_t* __restrict__ Wfcb,
    float* __restrict__ bias0, float* __restrict__ bias1,
    bf16_t* __restrict__ mh0, bf16_t* __restrict__ mh1,
    float* __restrict__ c0, float* __restrict__ c1,
    unsigned* __restrict__ sync)
{
    const unsigned stride = gridDim.x * blockDim.x;
    const unsigned i0 = blockIdx.x * blockDim.x + threadIdx.x;

    for (unsigned i = i0; i < SYNC_N; i += stride) sync[i] = 0u;

    for (unsigned i = i0; i < 4096u * LD1; i += stride) {
        unsigned m = i >> 11, kk = i & 2047u;
        float v = (kk < HID) ? Wih1[m * HID + kk] : Whh1[m * HID + (kk - HID)];
        Wcat1[i] = (bf16_t)v;
    }
    for (unsigned i = i0; i < 4096u * LD0; i += stride) {
        unsigned m = i / LD0, kk = i - m * LD0;
        float v = (kk < FIN) ? Wih0[m * FIN + kk] : Whh0[m * HID + (kk - FIN)];
        Wcat0[i] = (bf16_t)v;
    }
    // x into fragment-swizzled layout
    for (unsigned i = i0; i < 4194304u; i += stride) {   // 128*512*64
        unsigned e = i & 7u, unit = i >> 3;
        unsigned lane = unit & 63u, g = unit >> 6;
        unsigned wvv = g & 7u, pt = g >> 3;              // pt = t*2 + p
        unsigned p = pt & 1u, t = pt >> 1;
        unsigned n = wvv * 16u + (lane & 15u);
        unsigned k = p * 32u + (lane >> 4) * 8u + e;
        xswz[i] = (bf16_t)x[((size_t)n * T_SEQ + t) * FIN + k];
    }
    for (unsigned i = i0; i < 64u * HID; i += stride)
        Wfcb[i] = (bf16_t)Wfc[i];
    for (unsigned i = i0; i < (unsigned)(DM * HB); i += stride) {
        mh0[i] = (bf16_t)0.0f; mh1[i] = (bf16_t)0.0f;    // slot DM-1 read as h[-1]=0
    }
    for (unsigned i = i0; i < (unsigned)HB; i += stride) { c0[i] = 0.0f; c1[i] = 0.0f; }
    for (unsigned i = i0; i < 4096u; i += stride) {
        bias0[i] = bih0[i] + bhh0[i];
        bias1[i] = bih1[i] + bhh1[i];
    }
}

// Persistent cooperative kernel: 192 blocks x 512 threads, 1 block/CU.
// Blocks 0..63 = L0 (64 gate-rows, K=1088); 64..191 = L1 (32 gate-rows, K=2048).
// Producers write master rings with write-through atomics; consumers read with
// PLAIN coalesced loads -- the XCD's own L2 aggregates the broadcast (stale-line
// safety: DM=32 ring => ~9x L2 capacity turnover between slot reuses).
// Sync: per-block flags (no RMW contention), wave-0 parallel polls + __all.
__global__ __launch_bounds__(512) void lstm_persist(
    const bf16_t* __restrict__ Wcat0, const bf16_t* __restrict__ Wcat1,
    const float* __restrict__ bias0, const float* __restrict__ bias1,
    const bf16_t* __restrict__ xswz,
    bf16_t* __restrict__ mh0,   // [DM][HB] master h0 ring (swizzled)
    bf16_t* __restrict__ mh1,   // [DM][HB] master h1 ring (swizzled)
    float* __restrict__ c0, float* __restrict__ c1,   // [HID][NB], block-private
    bf16_t* __restrict__ h2buf, // [NB][T][HID] layer1 history for FC
    unsigned* __restrict__ sync)
{
    extern __shared__ bf16_t Wl[];
    const int b = blockIdx.x;
    const int tid = threadIdx.x;
    const int layer = (b >= 64);

    // ---- one-time weight gather into LDS (rows ordered u*4+gate) ----
    bf16_t* stage;
    if (!layer) {
        const int g0 = b;
        for (int c = tid; c < 64 * (LD0 / 8); c += 512) {
            int r = c / (LD0 / 8), off = (c % (LD0 / 8)) * 8;
            int u = r >> 2, gate = r & 3;
            *(bf16x8*)(Wl + r * ST0 + off) =
                *(const bf16x8*)(Wcat0 + (size_t)(gate * HID + g0 * 16 + u) * LD0 + off);
        }
        stage = Wl + 64 * ST0;
    } else {
        const int g1 = b - 64;
        for (int c = tid; c < 32 * (LD1 / 8); c += 512) {
            int r = c >> 8, off = (c & 255) * 8;
            int u = r >> 2, gate = r & 3;
            *(bf16x8*)(Wl + r * ST1 + off) =
                *(const bf16x8*)(Wcat1 + (size_t)(gate * HID + g1 * 8 + u) * LD1 + off);
        }
        stage = Wl + 32 * ST1;
    }
    __syncthreads();

    const int wv = tid >> 6;
    const int lane = tid & 63;
    const int q = lane >> 4;
    const int l = lane & 15;
    const int nn = wv * 16 + l;

    for (int t = 0; t < T_SEQ; ++t) {
        if (!layer) {
            const int g0 = b;
            f32x4 acc[4] = {{0.f,0.f,0.f,0.f},{0.f,0.f,0.f,0.f},{0.f,0.f,0.f,0.f},{0.f,0.f,0.f,0.f}};
            // x panels: no dependency, compute BEFORE the wait
            {
                const bf16_t* X = xswz + (((size_t)t * 2) * 8) * 64 * 8;
#pragma unroll
                for (int p = 0; p < 2; ++p) {
                    bf16x8 bv = *(const bf16x8*)(X + (((size_t)p * 8 + wv) * 64 + lane) * 8);
#pragma unroll
                    for (int mt = 0; mt < 4; ++mt) {
                        bf16x8 av = *(const bf16x8*)(Wl + (mt * 16 + l) * ST0 + p * 32 + q * 8);
                        acc[mt] = __builtin_amdgcn_mfma_f32_16x16x32_bf16(av, bv, acc[mt], 0, 0, 0);
                    }
                }
            }
            // wait: f0 all >= t (own chain; h0[t-1] readable+slot reuse safe),
            //       f1 all >= t-31 (mh0 ring-overwrite guard)
            __syncthreads();
            if (wv == 0) {
                const unsigned tA = (unsigned)t;
                const unsigned tB = (t >= DM) ? (unsigned)(t - (DM - 1)) : 0u;
                for (;;) {
                    bool ok = (ldcnt(&sync[F0 + lane]) >= tA)
                           && (ldcnt(&sync[F1 + lane]) >= tB)
                           && (ldcnt(&sync[F1 + 64 + lane]) >= tB);
                    if (__all(ok)) break;
                    __builtin_amdgcn_s_sleep(1);
                }
            }
            __syncthreads();
            // h panels from mh0 slot (t-1): plain coalesced loads (L2-aggregated)
            {
                const bf16_t* B = mh0 + (size_t)((t + DM - 1) & (DM - 1)) * HB;
                bf16x8 bb[8];
#pragma unroll
                for (int i = 0; i < 8; ++i)
                    bb[i] = *(const bf16x8*)(B + (((size_t)i * 8 + wv) * 64 + lane) * 8);
#pragma unroll
                for (int p = 0; p < 32; ++p) {
                    bf16x8 bv = bb[p & 7];
#pragma unroll
                    for (int mt = 0; mt < 4; ++mt) {
                        bf16x8 av = *(const bf16x8*)(Wl + (mt * 16 + l) * ST0 + FIN + p * 32 + q * 8);
                        acc[mt] = __builtin_amdgcn_mfma_f32_16x16x32_bf16(av, bv, acc[mt], 0, 0, 0);
                    }
                    if (p + 8 < 32)
                        bb[p & 7] = *(const bf16x8*)(B + (((size_t)(p + 8) * 8 + wv) * 64 + lane) * 8);
                }
            }
            // lane-local cell update -> stage
#pragma unroll
            for (int mt = 0; mt < 4; ++mt) {
                const int u = mt * 4 + q, j = g0 * 16 + u;
                float iv = sigm_f(acc[mt][0] + bias0[j]);
                float fv = sigm_f(acc[mt][1] + bias0[HID + j]);
                float gv = tanh_f(acc[mt][2] + bias0[2 * HID + j]);
                float ov = sigm_f(acc[mt][3] + bias0[3 * HID + j]);
                const size_t ci = (size_t)j * NB + nn;
                float cn = fv * c0[ci] + iv * gv;
                c0[ci] = cn;
                stage[nn * 16 + u] = (bf16_t)(ov * tanh_f(cn));
            }
            __syncthreads();
            if (tid < 256) {   // master write, swizzled, write-through
                const int n = tid >> 1, half = tid & 1;
                u64 v0 = *(const u64*)(stage + n * 16 + half * 8);
                u64 v1 = *(const u64*)(stage + n * 16 + half * 8 + 4);
                size_t unit = ((size_t)((g0 >> 1) * 8 + (n >> 4))) * 64
                              + ((g0 & 1) * 2 + half) * 16 + (n & 15);
                u64* dst = (u64*)(mh0 + (size_t)(t & (DM - 1)) * HB) + unit * 2;
                stw64(dst, v0); stw64(dst + 1, v1);
            }
            __syncthreads();   // all waves' stores drained (vmcnt 0 at barrier)
            if (tid == 0) stw32(&sync[F0 + g0], (unsigned)(t + 1));
        } else {
            const int g1 = b - 64;
            // waitA: f1 all >= t (own chain: h1[t-1] readable, mh1 slot reuse safe)
            __syncthreads();
            if (wv == 0) {
                const unsigned tA = (unsigned)t;
                for (;;) {
                    bool ok = (ldcnt(&sync[F1 + lane]) >= tA)
                           && (ldcnt(&sync[F1 + 64 + lane]) >= tA);
                    if (__all(ok)) break;
                    __builtin_amdgcn_s_sleep(1);
                }
            }
            __syncthreads();
            f32x4 acc[2] = {{0.f,0.f,0.f,0.f},{0.f,0.f,0.f,0.f}};
            // h1[t-1] half first (A-cols HID+...), hides the f0 dependency
            {
                const bf16_t* B1 = mh1 + (size_t)((t + DM - 1) & (DM - 1)) * HB;
                bf16x8 bb[8];
#pragma unroll
                for (int i = 0; i < 8; ++i)
                    bb[i] = *(const bf16x8*)(B1 + (((size_t)i * 8 + wv) * 64 + lane) * 8);
#pragma unroll
                for (int p = 0; p < 32; ++p) {
                    bf16x8 bv = bb[p & 7];
#pragma unroll
                    for (int mt = 0; mt < 2; ++mt) {
                        bf16x8 av = *(const bf16x8*)(Wl + (mt * 16 + l) * ST1 + HID + p * 32 + q * 8);
                        acc[mt] = __builtin_amdgcn_mfma_f32_16x16x32_bf16(av, bv, acc[mt], 0, 0, 0);
                    }
                    if (p + 8 < 32)
                        bb[p & 7] = *(const bf16x8*)(B1 + (((size_t)(p + 8) * 8 + wv) * 64 + lane) * 8);
                }
            }
            // waitB: f0 all >= t+1 (h0[t] ready; pre-satisfied when L0 leads)
            __syncthreads();
            if (wv == 0) {
                const unsigned tB = (unsigned)(t + 1);
                for (;;) {
                    bool ok = (ldcnt(&sync[F0 + lane]) >= tB);
                    if (__all(ok)) break;
                    __builtin_amdgcn_s_sleep(1);
                }
            }
            __syncthreads();
            // h0[t] half
            {
                const bf16_t* B0 = mh0 + (size_t)(t & (DM - 1)) * HB;
                bf16x8 bb[8];
#pragma unroll
                for (int i = 0; i < 8; ++i)
                    bb[i] = *(const bf16x8*)(B0 + (((size_t)i * 8 + wv) * 64 + lane) * 8);
#pragma unroll
                for (int p = 0; p < 32; ++p) {
                    bf16x8 bv = bb[p & 7];
#pragma unroll
                    for (int mt = 0; mt < 2; ++mt) {
                        bf16x8 av = *(const bf16x8*)(Wl + (mt * 16 + l) * ST1 + p * 32 + q * 8);
                        acc[mt] = __builtin_amdgcn_mfma_f32_16x16x32_bf16(av, bv, acc[mt], 0, 0, 0);
                    }
                    if (p + 8 < 32)
                        bb[p & 7] = *(const bf16x8*)(B0 + (((size_t)(p + 8) * 8 + wv) * 64 + lane) * 8);
                }
            }
#pragma unroll
            for (int mt = 0; mt < 2; ++mt) {
                const int u = mt * 4 + q, j = g1 * 8 + u;
                float iv = sigm_f(acc[mt][0] + bias1[j]);
                float fv = sigm_f(acc[mt][1] + bias1[HID + j]);
                float gv = tanh_f(acc[mt][2] + bias1[2 * HID + j]);
                float ov = sigm_f(acc[mt][3] + bias1[3 * HID + j]);
                const size_t ci = (size_t)j * NB + nn;
                float cn = fv * c1[ci] + iv * gv;
                c1[ci] = cn;
                stage[nn * 8 + u] = (bf16_t)(ov * tanh_f(cn));
            }
            __syncthreads();
            if (tid < 128) {   // master write (swizzled, write-through)
                const int n = tid;
                u64 v0 = *(const u64*)(stage + n * 8);
                u64 v1 = *(const u64*)(stage + n * 8 + 4);
                size_t unit = ((size_t)((g1 >> 2) * 8 + (n >> 4))) * 64
                              + (g1 & 3) * 16 + (n & 15);
                u64* dst = (u64*)(mh1 + (size_t)(t & (DM - 1)) * HB) + unit * 2;
                stw64(dst, v0); stw64(dst + 1, v1);
            }
            if (tid < 256) {   // h2 history (normal stores; read by fc_kernel)
                const int n = tid >> 1, part = tid & 1;
                *(u64*)(h2buf + ((size_t)n * T_SEQ + t) * HID + g1 * 8 + part * 4) =
                    *(const u64*)(stage + n * 8 + part * 4);
            }
            __syncthreads();   // drain
            if (tid == 0) stw32(&sync[F1 + g1], (unsigned)(t + 1));
        }
    }
}

// Final FC: out[m][o] = h2[m][:] @ Wfc[o][:] + bfc[o], m = n*T + t.
__global__ __launch_bounds__(256) void fc_kernel(
    const bf16_t* __restrict__ h2buf, const bf16_t* __restrict__ Wfcb,
    const float* __restrict__ bfc, float* __restrict__ out)
{
    const int tid = threadIdx.x, wv = tid >> 6, lane = tid & 63;
    const int q = lane >> 4, l = lane & 15;
    const int m0 = blockIdx.x * 64 + wv * 16;
    const bf16_t* arow = h2buf + (size_t)(m0 + l) * HID + q * 8;
    const bf16_t* brow = Wfcb + (size_t)l * HID + q * 8;
    f32x4 acc[4] = {{0.f,0.f,0.f,0.f},{0.f,0.f,0.f,0.f},{0.f,0.f,0.f,0.f},{0.f,0.f,0.f,0.f}};
#pragma unroll 4
    for (int p = 0; p < 32; ++p) {
        bf16x8 av = *(const bf16x8*)(arow + p * 32);
#pragma unroll
        for (int ntile = 0; ntile < 4; ++ntile) {
            bf16x8 bv = *(const bf16x8*)(brow + (size_t)ntile * 16 * HID + p * 32);
            acc[ntile] = __builtin_amdgcn_mfma_f32_16x16x32_bf16(av, bv, acc[ntile], 0, 0, 0);
        }
    }
#pragma unroll
    for (int ntile = 0; ntile < 4; ++ntile) {
        float bv = bfc[ntile * 16 + l];
#pragma unroll
        for (int r = 0; r < 4; ++r)
            out[(size_t)(m0 + q * 4 + r) * 64 + ntile * 16 + l] = acc[ntile][r] + bv;
    }
}

extern "C" void kernel_launch(void* const* d_in, const int* in_sizes, int n_in,
                              void* d_out, int out_size, void* d_ws, size_t ws_size,
                              hipStream_t stream)
{
    const float* x    = (const float*)d_in[0];
    const float* Wih0 = (const float*)d_in[1];
    const float* Whh0 = (const float*)d_in[2];
    const float* bih0 = (const float*)d_in[3];
    const float* bhh0 = (const float*)d_in[4];
    const float* Wih1 = (const float*)d_in[5];
    const float* Whh1 = (const float*)d_in[6];
    const float* bih1 = (const float*)d_in[7];
    const float* bhh1 = (const float*)d_in[8];
    const float* Wfc  = (const float*)d_in[9];
    const float* bfc  = (const float*)d_in[10];
    float* out = (float*)d_out;

    char* ws = (char*)d_ws;
    size_t off = 0;
    auto alloc = [&](size_t bytes) -> void* {
        void* p = ws + off;
        off += (bytes + 255) & ~(size_t)255;
        return p;
    };
    bf16_t* Wcat0 = (bf16_t*)alloc((size_t)4096 * LD0 * 2);           // 8.9 MB
    bf16_t* Wcat1 = (bf16_t*)alloc((size_t)4096 * LD1 * 2);           // 16.8 MB
    bf16_t* xswz  = (bf16_t*)alloc((size_t)NB * T_SEQ * FIN * 2);     // 8.4 MB
    bf16_t* h2buf = (bf16_t*)alloc((size_t)NB * T_SEQ * HID * 2);     // 134 MB
    bf16_t* mh0   = (bf16_t*)alloc((size_t)DM * HB * 2);              // 8.4 MB
    bf16_t* mh1   = (bf16_t*)alloc((size_t)DM * HB * 2);              // 8.4 MB
    float*  c0    = (float*)alloc((size_t)HB * 4);
    float*  c1    = (float*)alloc((size_t)HB * 4);
    float*  bias0 = (float*)alloc(4096 * 4);
    float*  bias1 = (float*)alloc(4096 * 4);
    bf16_t* Wfcb  = (bf16_t*)alloc((size_t)64 * HID * 2);
    unsigned* syncp = (unsigned*)alloc(SYNC_N * 4);
    if (off > ws_size) return;

    hipFuncSetAttribute((const void*)lstm_persist,
                        hipFuncAttributeMaxDynamicSharedMemorySize, LDS_BYTES);

    prep_kernel<<<1024, 256, 0, stream>>>(x, Wih0, Whh0, bih0, bhh0,
                                          Wih1, Whh1, bih1, bhh1, Wfc,
                                          Wcat0, Wcat1, xswz, Wfcb,
                                          bias0, bias1, mh0, mh1,
                                          c0, c1, syncp);

    void* args[] = { (void*)&Wcat0, (void*)&Wcat1, (void*)&bias0, (void*)&bias1,
                     (void*)&xswz, (void*)&mh0, (void*)&mh1,
                     (void*)&c0, (void*)&c1, (void*)&h2buf, (void*)&syncp };
    hipLaunchCooperativeKernel((void*)lstm_persist, dim3(NBLK), dim3(512),
                               args, LDS_BYTES, stream);

    fc_kernel<<<(NB * T_SEQ) / 64, 256, 0, stream>>>(h2buf, Wfcb, bfc, out);
}